// Round 1
// 281.348 us; speedup vs baseline: 1.0134x; 1.0134x over previous
//
#include <hip/hip_runtime.h>

typedef short bf16x8 __attribute__((ext_vector_type(8)));
typedef float f32x4 __attribute__((ext_vector_type(4)));

#define NN 10000
#define EE 160000
#define BB 4
#define TTT 12
#define FFF 16
#define CCC 64
#define BT 48      // BB*TTT
#define NF 768     // BT*FFF
#define SLOTS 64   // padded adjacency slots per node (P[deg>64] ~ 1e-20 for Poisson(16))

#define TCS 72     // tcat row stride (bf16)
#define SPS 72     // sp row stride (bf16): 144B = 36 banks; rows r,r+4 land 16 banks apart
#define HMS 68     // hmat row stride (f32): 272B = 17x16B slots (odd)

// workspace byte offsets (256B aligned)
#define WS_DEG     0u                  // float[10000]
#define WS_CNT     40960u              // int[10000] (atomic cursors -> final = deg)
#define WS_CWT     81920u              // ushort[4096]
#define WS_RWTB    90112u              // ushort[2048]
#define WS_WKT     94208u              // ushort[12288]
#define WS_CSRP    118784u             // int[10000*64], memset 0x7F -> clamp to NN
#define WS_VBF     2678784u            // ushort[10001*768]
#define WS_TX1BF   18040320u           // ushort[10001*768]  (ends ~33.4 MB)

__device__ __forceinline__ unsigned short f2bf(float x){
    unsigned int u = __float_as_uint(x);
    u += 0x7FFFu + ((u >> 16) & 1u);
    return (unsigned short)(u >> 16);
}
__device__ __forceinline__ float bf2f(unsigned short h){
    return __uint_as_float(((unsigned int)h) << 16);
}

// clamp pad slots (0x7F7F7F7F from memset) to the dummy zero row NN
#define GMIN4(E)                                                                  \
    E.x = E.x < NN ? E.x : NN; E.y = E.y < NN ? E.y : NN;                         \
    E.z = E.z < NN ? E.z : NN; E.w = E.w < NN ? E.w : NN;

#define GATHER8(SRC, EA, EB, ACC0, ACC1, ACC2, ACC3, Q)                           \
    {                                                                             \
        ushort4 p0 = *(const ushort4*)&SRC[(size_t)EA.x * NF + (Q) * 4];          \
        ushort4 p1 = *(const ushort4*)&SRC[(size_t)EA.y * NF + (Q) * 4];          \
        ushort4 p2 = *(const ushort4*)&SRC[(size_t)EA.z * NF + (Q) * 4];          \
        ushort4 p3 = *(const ushort4*)&SRC[(size_t)EA.w * NF + (Q) * 4];          \
        ushort4 p4 = *(const ushort4*)&SRC[(size_t)EB.x * NF + (Q) * 4];          \
        ushort4 p5 = *(const ushort4*)&SRC[(size_t)EB.y * NF + (Q) * 4];          \
        ushort4 p6 = *(const ushort4*)&SRC[(size_t)EB.z * NF + (Q) * 4];          \
        ushort4 p7 = *(const ushort4*)&SRC[(size_t)EB.w * NF + (Q) * 4];          \
        ACC0 += bf2f(p0.x)+bf2f(p1.x)+bf2f(p2.x)+bf2f(p3.x)                       \
              + bf2f(p4.x)+bf2f(p5.x)+bf2f(p6.x)+bf2f(p7.x);                      \
        ACC1 += bf2f(p0.y)+bf2f(p1.y)+bf2f(p2.y)+bf2f(p3.y)                       \
              + bf2f(p4.y)+bf2f(p5.y)+bf2f(p6.y)+bf2f(p7.y);                      \
        ACC2 += bf2f(p0.z)+bf2f(p1.z)+bf2f(p2.z)+bf2f(p3.z)                       \
              + bf2f(p4.z)+bf2f(p5.z)+bf2f(p6.z)+bf2f(p7.z);                      \
        ACC3 += bf2f(p0.w)+bf2f(p1.w)+bf2f(p2.w)+bf2f(p3.w)                       \
              + bf2f(p4.w)+bf2f(p5.w)+bf2f(p6.w)+bf2f(p7.w);                      \
    }

// fused setup grid (3198 blocks):
//   [0,625)      deg atomic count
//   [625,1250)   fillpad (merged; csrp pre-init'd by 0x7F memset)
//   [1250,3125)  buildv: register-only transpose, 48 threads/node, 480000 threads
//   3125         zero dummy rows
//   [3126,3198)  weight transposes
__global__ __launch_bounds__(256) void k_setup(
    const float* __restrict__ x, const int* __restrict__ ei,
    const float* __restrict__ chW, const float* __restrict__ tW, const float* __restrict__ rW,
    float* __restrict__ deg, int* __restrict__ cnt, int* __restrict__ csrp,
    unsigned short* __restrict__ vbf, unsigned short* __restrict__ tx1bf,
    unsigned short* __restrict__ cWt, unsigned short* __restrict__ rWtb,
    unsigned short* __restrict__ wkt)
{
    int bid = blockIdx.x, tid = threadIdx.x;
    if (bid < 625){
        int e = bid * 256 + tid;
        if (e < EE) atomicAdd(&deg[ei[e]], 1.0f);
    } else if (bid < 1250){
        int e = (bid - 625) * 256 + tid;
        if (e < EE){
            int c = ei[EE + e];
            int slot = atomicAdd(&cnt[c], 1);
            if (slot < SLOTS) csrp[c * SLOTS + slot] = ei[e];
        }
    } else if (bid < 3125){
        int u = (bid - 1250) * 256 + tid;            // < 480000
        int n = u / 48, r = u - n * 48;
        int t = r >> 2, j = r & 3;                   // f = 4j+i
        #pragma unroll
        for (int b = 0; b < BB; ++b){
            const float* xp = x + (size_t)(b * NN + n) * 192;
            ushort4 w = { f2bf(xp[(4 * j + 0) * 12 + t]),
                          f2bf(xp[(4 * j + 1) * 12 + t]),
                          f2bf(xp[(4 * j + 2) * 12 + t]),
                          f2bf(xp[(4 * j + 3) * 12 + t]) };
            *(ushort4*)&vbf[(size_t)n * NF + b * 192 + t * 16 + j * 4] = w;
        }
    } else if (bid == 3125){
        if (tid < 192){
            ushort4 z = { 0, 0, 0, 0 };
            *(ushort4*)&vbf[(size_t)NN * NF + tid * 4]   = z;
            *(ushort4*)&tx1bf[(size_t)NN * NF + tid * 4] = z;
        }
    } else {
        int idx = (bid - 3126) * 256 + tid;          // < 18432
        if (idx < 4096){                      // cWt[c][k], k = kk*16+f (48 real, pad 0)
            int c = idx >> 6, k = idx & 63;
            float v = 0.f;
            if (k < 48){ int kk = k >> 4, f = k & 15; v = chW[kk * 1024 + f * 64 + c]; }
            cWt[idx] = f2bf(v);
        } else if (idx < 6144){               // rWtb[o][k], k<16 = f, pad 0
            int j = idx - 4096;
            int o = j >> 5, k = j & 31;
            float v = (k < 16) ? rW[o * 16 + k] : 0.f;
            rWtb[j] = f2bf(v);
        } else {                              // wkt[kk][o][dc]
            int j = idx - 6144;
            int kk = j >> 12; int r2 = j & 4095;
            int o = r2 >> 6, dc = r2 & 63;
            wkt[j] = f2bf(tW[(o * 64 + dc) * 3 + kk]);
        }
    }
}

// tx1 = (2/lam)*(deg*v - agg) - v ; 16-deep gather pipeline (2x MLP vs 8)
__global__ __launch_bounds__(192) void k_lhat(
        const unsigned short* __restrict__ vbf, const float* __restrict__ deg,
        const int* __restrict__ cnt, const int* __restrict__ csrp,
        const float* __restrict__ lam, unsigned short* __restrict__ tx1bf){
    int n = blockIdx.x;
    int q = threadIdx.x;
    float s2 = 2.0f / lam[0];
    float dn = deg[n];
    int c = cnt[n]; c = c > SLOTS ? SLOTS : c;
    int iters = (c + 15) >> 4;
    const int4* cp = (const int4*)(csrp + n * SLOTS);
    float a0 = 0.f, a1 = 0.f, a2 = 0.f, a3 = 0.f;
    for (int it = 0; it < iters; ++it){
        int4 e0 = cp[it * 4], e1 = cp[it * 4 + 1];
        int4 e2 = cp[it * 4 + 2], e3 = cp[it * 4 + 3];
        GMIN4(e0) GMIN4(e1) GMIN4(e2) GMIN4(e3)
        GATHER8(vbf, e0, e1, a0, a1, a2, a3, q);
        GATHER8(vbf, e2, e3, a0, a1, a2, a3, q);
    }
    ushort4 hv = *(const ushort4*)&vbf[(size_t)n * NF + q * 4];
    float v0 = bf2f(hv.x), v1 = bf2f(hv.y), v2 = bf2f(hv.z), v3 = bf2f(hv.w);
    ushort4 o4 = { f2bf(s2 * (dn * v0 - a0) - v0),
                   f2bf(s2 * (dn * v1 - a1) - v1),
                   f2bf(s2 * (dn * v2 - a2) - v2),
                   f2bf(s2 * (dn * v3 - a3) - v3) };
    *(ushort4*)&tx1bf[(size_t)n * NF + q * 4] = o4;
}

// per-node fused: gather->Tcat(bf16) -> MFMA Cheb+resid -> sp(bf16) -> MFMA
// temporal conv -> hmat -> LayerNorm -> out
// LDS union: [spl | red] (8064B) + [tcat | hmat] (13056B) = 21120B -> 7 blocks/CU
__global__ __launch_bounds__(256) void k_fused(
    const unsigned short* __restrict__ vbf, const unsigned short* __restrict__ tx1bf,
    const float* __restrict__ deg, const int* __restrict__ cnt, const int* __restrict__ csrp,
    const float* __restrict__ lam,
    const unsigned short* __restrict__ cWt, const float* __restrict__ chebB,
    const unsigned short* __restrict__ wkt, const float* __restrict__ timeB,
    const unsigned short* __restrict__ rWtb, const float* __restrict__ resB,
    const float* __restrict__ gamma, const float* __restrict__ beta,
    float* __restrict__ out)
{
    __shared__ __align__(16) char smem[21120];
    unsigned short* spl  = (unsigned short*)smem;            // 56*SPS bf16 (phases B-D)
    float2*         red  = (float2*)smem;                    // 48 float2 (overlays dead spl)
    unsigned short* tcat = (unsigned short*)(smem + 8064);   // 48*TCS bf16 (phases A-B)
    float*          hmat = (float*)(smem + 8064);            // 48*HMS f32 (phase D+, overlays tcat)

    int n = blockIdx.x;
    int tid = threadIdx.x;

    // ---- zero sp pad rows (p=0, p=13 per b) ----
    {
        int rid = tid >> 5;
        int cc = tid & 31;
        int b = rid >> 1, p = (rid & 1) * 13;
        *(unsigned int*)&spl[(b * 14 + p) * SPS + cc * 2] = 0u;
    }

    // ---- phase A: 8-way unrolled padded gather + build Tcat (bf16) ----
    if (tid < 192){
        float s2 = 2.0f / lam[0];
        float dn = deg[n];
        ushort4 hv = *(const ushort4*)&vbf[(size_t)n * NF + tid * 4];
        ushort4 hu = *(const ushort4*)&tx1bf[(size_t)n * NF + tid * 4];
        float a0 = 0.f, a1 = 0.f, a2 = 0.f, a3 = 0.f;
        int c = cnt[n]; c = c > SLOTS ? SLOTS : c;
        int iters = (c + 7) >> 3;
        const int4* cp = (const int4*)(csrp + n * SLOTS);
        for (int it = 0; it < iters; ++it){
            int4 e0 = cp[it * 2], e1 = cp[it * 2 + 1];
            GMIN4(e0) GMIN4(e1)
            GATHER8(tx1bf, e0, e1, a0, a1, a2, a3, tid);
        }
        float u0 = bf2f(hu.x), u1 = bf2f(hu.y), u2 = bf2f(hu.z), u3 = bf2f(hu.w);
        float v0 = bf2f(hv.x), v1 = bf2f(hv.y), v2 = bf2f(hv.z), v3 = bf2f(hv.w);
        ushort4 w2 = { f2bf(2.0f * (s2 * (dn * u0 - a0) - u0) - v0),
                       f2bf(2.0f * (s2 * (dn * u1 - a1) - u1) - v1),
                       f2bf(2.0f * (s2 * (dn * u2 - a2) - u2) - v2),
                       f2bf(2.0f * (s2 * (dn * u3 - a3) - u3) - v3) };
        ushort4 zz = { 0, 0, 0, 0 };
        int bt = tid >> 2, ch = tid & 3;
        *(ushort4*)&tcat[bt * TCS +      ch * 4] = hv;   // T0
        *(ushort4*)&tcat[bt * TCS + 16 + ch * 4] = hu;   // T1
        *(ushort4*)&tcat[bt * TCS + 32 + ch * 4] = w2;   // T2
        *(ushort4*)&tcat[bt * TCS + 48 + ch * 4] = zz;   // zero K-pad
    }
    __syncthreads();

    int lane = tid & 63;
    int nt   = tid >> 6;
    int ln   = lane & 15;
    int quad = lane >> 4;
    int q8   = quad * 8;
    int col  = nt * 16 + ln;

    // ---- phase B: Cheb GEMM (K=64) + residual GEMM ----
    {
        bf16x8 cb0 = *(const bf16x8*)&cWt[col * 64 + q8];
        bf16x8 cb1 = *(const bf16x8*)&cWt[col * 64 + 32 + q8];
        bf16x8 rb  = *(const bf16x8*)&rWtb[col * 32 + q8];
        f32x4 cacc[3], racc[3];
        #pragma unroll
        for (int mt = 0; mt < 3; ++mt){
            bf16x8 a0 = *(const bf16x8*)&tcat[(mt * 16 + ln) * TCS + q8];
            bf16x8 a1 = *(const bf16x8*)&tcat[(mt * 16 + ln) * TCS + 32 + q8];
            f32x4 z = {0.f, 0.f, 0.f, 0.f};
            cacc[mt] = __builtin_amdgcn_mfma_f32_16x16x32_bf16(a0, cb0, z, 0, 0, 0);
            cacc[mt] = __builtin_amdgcn_mfma_f32_16x16x32_bf16(a1, cb1, cacc[mt], 0, 0, 0);
            racc[mt] = __builtin_amdgcn_mfma_f32_16x16x32_bf16(a0, rb, z, 0, 0, 0);
        }
        float cb = chebB[col];
        #pragma unroll
        for (int mt = 0; mt < 3; ++mt){
            #pragma unroll
            for (int i = 0; i < 4; ++i){
                int r = mt * 16 + quad * 4 + i;
                int bb = (r * 43) >> 9;
                int tt = r - 12 * bb;
                float val = fmaxf(cacc[mt][i] + cb, 0.0f);
                spl[(bb * 14 + tt + 1) * SPS + col] = f2bf(val);
            }
        }
        __syncthreads();   // tcat dead from here; hmat may overwrite it

        // ---- phase D: temporal conv = 3 shifted GEMMs ----
        bf16x8 wb[3][2];
        #pragma unroll
        for (int kk = 0; kk < 3; ++kk){
            wb[kk][0] = *(const bf16x8*)&wkt[kk * 4096 + col * 64 + q8];
            wb[kk][1] = *(const bf16x8*)&wkt[kk * 4096 + col * 64 + 32 + q8];
        }
        float tb = timeB[col] + resB[col];
        #pragma unroll
        for (int mt = 0; mt < 3; ++mt){
            int bt = mt * 16 + ln;
            int bb = (bt * 43) >> 9;
            int tt = bt - 12 * bb;
            int rbase = bb * 14 + tt;
            f32x4 tacc = {0.f, 0.f, 0.f, 0.f};
            #pragma unroll
            for (int kk = 0; kk < 3; ++kk){
                bf16x8 a0 = *(const bf16x8*)&spl[(rbase + kk) * SPS + q8];
                bf16x8 a1 = *(const bf16x8*)&spl[(rbase + kk) * SPS + 32 + q8];
                tacc = __builtin_amdgcn_mfma_f32_16x16x32_bf16(a0, wb[kk][0], tacc, 0, 0, 0);
                tacc = __builtin_amdgcn_mfma_f32_16x16x32_bf16(a1, wb[kk][1], tacc, 0, 0, 0);
            }
            #pragma unroll
            for (int i = 0; i < 4; ++i){
                int r = mt * 16 + quad * 4 + i;
                float h = fmaxf(tacc[i] + racc[mt][i] + tb, 0.0f);
                hmat[r * HMS + col] = h;
            }
        }
    }
    __syncthreads();   // spl dead from here; red may overwrite it

    // ---- LN partial sums: 4 lanes per row ----
    if (tid < 192){
        int row = tid >> 2, p = tid & 3;
        const float4* h4 = (const float4*)&hmat[row * HMS + p * 16];
        float4 A = h4[0], Bv = h4[1], Cv = h4[2], Dv = h4[3];
        float s = A.x+A.y+A.z+A.w + Bv.x+Bv.y+Bv.z+Bv.w
                + Cv.x+Cv.y+Cv.z+Cv.w + Dv.x+Dv.y+Dv.z+Dv.w;
        float q = A.x*A.x+A.y*A.y+A.z*A.z+A.w*A.w + Bv.x*Bv.x+Bv.y*Bv.y+Bv.z*Bv.z+Bv.w*Bv.w
                + Cv.x*Cv.x+Cv.y*Cv.y+Cv.z*Cv.z+Cv.w*Cv.w + Dv.x*Dv.x+Dv.y*Dv.y+Dv.z*Dv.z+Dv.w*Dv.w;
        s += __shfl_xor(s, 1); q += __shfl_xor(q, 1);
        s += __shfl_xor(s, 2); q += __shfl_xor(q, 2);
        if (p == 0) red[row] = make_float2(s, q);
    }
    __syncthreads();

    // ---- normalize + store ----
    {
        int g = nt, o = lane;
        float gam = gamma[o], bet = beta[o];
        float res[12];
        #pragma unroll
        for (int t = 0; t < 12; ++t){
            int row = g * 12 + t;
            float h = hmat[row * HMS + o];
            float2 m = red[row];
            float mu  = m.x * (1.0f / 64.0f);
            float var = m.y * (1.0f / 64.0f) - mu * mu;
            float r   = rsqrtf(var + 1e-5f);
            res[t] = (h - mu) * r * gam + bet;
        }
        size_t obase = ((size_t)(g * NN + n) * CCC + o) * TTT;
        float4* op = (float4*)(out + obase);
        op[0] = make_float4(res[0], res[1], res[2],  res[3]);
        op[1] = make_float4(res[4], res[5], res[6],  res[7]);
        op[2] = make_float4(res[8], res[9], res[10], res[11]);
    }
}

extern "C" void kernel_launch(void* const* d_in, const int* in_sizes, int n_in,
                              void* d_out, int out_size, void* d_ws, size_t ws_size,
                              hipStream_t stream)
{
    (void)in_sizes; (void)n_in; (void)out_size; (void)ws_size;
    const float* x   = (const float*)d_in[0];
    const int*   ei  = (const int*)  d_in[1];
    const float* lam = (const float*)d_in[2];
    const float* chW = (const float*)d_in[3];
    const float* chB = (const float*)d_in[4];
    const float* tW  = (const float*)d_in[5];
    const float* tB  = (const float*)d_in[6];
    const float* rW  = (const float*)d_in[7];
    const float* rB  = (const float*)d_in[8];
    const float* gam = (const float*)d_in[9];
    const float* bet = (const float*)d_in[10];
    float* out = (float*)d_out;

    char* ws = (char*)d_ws;
    float* deg  = (float*)(ws + WS_DEG);
    int*   cnt  = (int*)  (ws + WS_CNT);
    unsigned short* cWt  = (unsigned short*)(ws + WS_CWT);
    unsigned short* rWtb = (unsigned short*)(ws + WS_RWTB);
    unsigned short* wkt  = (unsigned short*)(ws + WS_WKT);
    int*   csrp = (int*)  (ws + WS_CSRP);
    unsigned short* vbf   = (unsigned short*)(ws + WS_VBF);
    unsigned short* tx1bf = (unsigned short*)(ws + WS_TX1BF);

    hipMemsetAsync(ws, 0, 81920, stream);                      // deg + cnt
    hipMemsetAsync(ws + WS_CSRP, 0x7F, NN * SLOTS * 4, stream); // csrp pad (clamped to NN)
    k_setup  <<<3198, 256, 0, stream>>>(x, ei, chW, tW, rW, deg, cnt, csrp,
                                        vbf, tx1bf, cWt, rWtb, wkt);
    k_lhat   <<<NN, 192, 0, stream>>>(vbf, deg, cnt, csrp, lam, tx1bf);
    k_fused  <<<NN, 256, 0, stream>>>(vbf, tx1bf, deg, cnt, csrp, lam,
                                      cWt, chB, wkt, tB, rWtb, rB, gam, bet, out);
}